// Round 12
// baseline (435.536 us; speedup 1.0000x reference)
//
#include <hip/hip_runtime.h>

typedef short short8 __attribute__((ext_vector_type(8)));
typedef float f32x4 __attribute__((ext_vector_type(4)));
typedef unsigned short ushort8_t __attribute__((ext_vector_type(8)));
typedef const __attribute__((address_space(1))) void gvoid_t;
typedef __attribute__((address_space(3))) void lvoid_t;

#define O_CH 128
#define I_CH 128
#define HW 112
#define PLANE (HW * HW)        // 12544
#define NCOL 114               // real cols (112 + 2 halo)
#define XPCOLS 128             // padded cols in Xp
// d_ws layout (DMA path): [0,8192) zero block | [8192,+294912) Wb | [303104,+117440512) Xp
#define WB_OFF   8192
#define XP_OFF   303104
#define WS_NEED  117743616ULL

__device__ __forceinline__ unsigned short f2bf(float f) {
  union { float f; unsigned u; } v; v.f = f;
  unsigned r = v.u + 0x7FFFu + ((v.u >> 16) & 1u);   // RNE (weights only)
  return (unsigned short)(r >> 16);
}

// one-instruction truncate-pack: [lo,hi] floats -> packed bf16 pair
__device__ __forceinline__ unsigned pktrunc(float lo, float hi) {
  union { float f; unsigned u; } a, b; a.f = lo; b.f = hi;
  return __builtin_amdgcn_perm(b.u, a.u, 0x07060302u);
}

__global__ void wsynth_kernel(const float* __restrict__ core,
                              const float* __restrict__ periph,
                              const float* __restrict__ thr,
                              const float* __restrict__ scale,
                              unsigned short* __restrict__ Wb) {
  int idx = blockIdx.x * blockDim.x + threadIdx.x;   // o*128 + i
  if (idx >= O_CH * I_CH) return;
  int o = idx >> 7;
  float c = core[idx];
  float s = scale[0];
  float g = 1.0f / (1.0f + __expf(-s * (fabsf(c) - thr[o])));
#pragma unroll
  for (int tap = 0; tap < 9; ++tap) {
    float p  = (tap == 4) ? 1.0f : periph[tap < 4 ? tap : tap - 1];
    float gg = (tap == 4) ? 1.0f : g;
    Wb[tap * (O_CH * I_CH) + idx] = f2bf(c * p * gg);   // layout [tap][o][i]
  }
}

__global__ void zfill_kernel(float* ws) {
  // zero the 8 KB zero block at d_ws+0
  float4* p = (float4*)ws;
  p[threadIdx.x * 2]     = make_float4(0.f, 0.f, 0.f, 0.f);
  p[threadIdx.x * 2 + 1] = make_float4(0.f, 0.f, 0.f, 0.f);
}

// X (NCHW f32) -> Xp[b][y][col 0..127][ch 0..127] bf16, col = input col + 1,
// out-of-range cols zeroed. LDS-tiled transpose.
__global__ __launch_bounds__(256) void xprep_kernel(const float* __restrict__ X,
                                                    unsigned short* __restrict__ Xp) {
  __shared__ float T[128 * 65];        // 33,280 B; +1 pad col stride
  const int wg = blockIdx.x;           // 32*112*2 = 7168
  const int b = wg / 224;
  const int rem = wg - b * 224;
  const int y = rem >> 1;
  const int cb = (rem & 1) * 64;       // Xp col base

  const int t = threadIdx.x;
  const int chq = t >> 2, part = t & 3;
#pragma unroll
  for (int i = 0; i < 2; ++i) {
    const int ch = i * 64 + chq;
    const float* xr = X + ((size_t)(b * I_CH + ch) * HW + y) * HW;
#pragma unroll
    for (int j = 0; j < 16; ++j) {
      const int c  = cb + part * 16 + j;
      const int ic = c - 1;
      T[ch * 65 + part * 16 + j] = (ic >= 0 && ic < HW) ? xr[ic] : 0.0f;
    }
  }
  __syncthreads();

  const int col = t & 63, chh = t >> 6;      // chh: 32-ch group
  const int c = cb + col;
  unsigned u[16];
#pragma unroll
  for (int q = 0; q < 16; ++q) {
    u[q] = pktrunc(T[(chh * 32 + 2 * q) * 65 + col],
                   T[(chh * 32 + 2 * q + 1) * 65 + col]);
  }
  uint4* dst = (uint4*)(Xp + ((size_t)(b * HW + y) * XPCOLS + c) * 128 + chh * 32);
#pragma unroll
  for (int q = 0; q < 4; ++q)
    dst[q] = make_uint4(u[q * 4], u[q * 4 + 1], u[q * 4 + 2], u[q * 4 + 3]);
}

// ============================ DMA conv path ============================
__global__ __launch_bounds__(256, 3)
void conv_dma(const unsigned short* __restrict__ Xp,
              const unsigned short* __restrict__ Wb,
              const char* __restrict__ zbase,
              float* __restrict__ Out) {
  // 2 buffers x [row 0..2][col 0..127][32 ch] bf16, LINEAR (DMA dest can't swizzle).
  // Read pattern verified min-conflict: addr16 mod 8 = (4(dx+ln)+lk4) mod 8 -> 8 lanes/residue.
  __shared__ unsigned short Xs[2 * 3 * XPCOLS * 32];   // 49,152 B -> 3 WGs/CU

  // XCD-chunked swizzle: 3584 = 8 XCDs x 448 (R6-verified)
  const int bid = blockIdx.x;
  const int L = (bid & 7) * 448 + (bid >> 3);
  const int b = L / HW;
  const int y = L - b * HW;

  const int t   = threadIdx.x;
  const int wv  = t >> 6;              // wave 0..3 -> o quarter
  const int l   = t & 63;
  const int ln  = l & 15;              // MFMA frag lane
  const int lk4 = l >> 4;              // k-slice 0..3

  f32x4 acc[2][7];
#pragma unroll
  for (int mr = 0; mr < 2; ++mr)
#pragma unroll
    for (int nf = 0; nf < 7; ++nf)
      acc[mr][nf] = (f32x4)0.0f;

  const unsigned short* wbase = Wb + (wv * 32 + ln) * I_CH + lk4 * 8;
  char* lds0 = (char*)Xs;

  // stage chunk K (32 ch) of rows y-1..y+1 into BUF via global_load_lds (DMA).
  // 6 instrs/thread x 16 B; linear16 = j*256+t: row = >>9, col = (rem>>2), part = rem&3.
#define STAGE_DMA(K, BUF)                                                       \
  _Pragma("unroll") for (int j = 0; j < 6; ++j) {                               \
    const int lin_  = j * 256 + t;                                              \
    const int row_  = lin_ >> 9;                                                \
    const int rem_  = lin_ & 511;                                               \
    const int irow_ = y - 1 + row_;                                             \
    const char* src_ = (irow_ >= 0 && irow_ < HW)                               \
        ? (const char*)Xp + ((size_t)(b * HW + irow_) * XPCOLS + (rem_ >> 2)) * 256 \
              + (K) * 64 + (rem_ & 3) * 16                                      \
        : zbase + rem_ * 16;                                                    \
    void* dst_ = (char*)(BUF) + j * 4096 + (t >> 6) * 1024;                     \
    __builtin_amdgcn_global_load_lds((gvoid_t*)src_, (lvoid_t*)dst_, 16, 0, 0); \
  }

  // A-fragment prefetch for global phase Q (tap set (Q%3)*3+dx, k-chunk Q/3)
#define APFETCH(D0, D1, Q)                                                      \
  _Pragma("unroll") for (int dx = 0; dx < 3; ++dx) {                            \
    const unsigned short* wp_ = wbase + (((Q) % 3) * 3 + dx) * (O_CH * I_CH)    \
                              + ((Q) / 3) * 32;                                 \
    D0[dx] = *reinterpret_cast<const short8*>(wp_);                             \
    D1[dx] = *reinterpret_cast<const short8*>(wp_ + 16 * I_CH);                 \
  }

#define COMPUTE_SUB_DMA(SUB, RB, S0, S1)                                        \
  _Pragma("unroll") for (int dx = 0; dx < 3; ++dx) {                            \
    const char* bp_ = (RB) + (SUB) * 8192 + (dx + ln) * 64 + lk4 * 16;          \
    _Pragma("unroll") for (int nf = 0; nf < 7; ++nf) {                          \
      short8 bb_ = *reinterpret_cast<const short8*>(bp_ + nf * 1024);           \
      acc[0][nf] = __builtin_amdgcn_mfma_f32_16x16x32_bf16(S0[dx], bb_, acc[0][nf], 0, 0, 0); \
      acc[1][nf] = __builtin_amdgcn_mfma_f32_16x16x32_bf16(S1[dx], bb_, acc[1][nf], 0, 0, 0); \
    }                                                                           \
  }

  short8 A0[3], A1[3], N0[3], N1[3];

  // ---- prologue: A for phase 0, DMA chunk 0 into buf0 ----
  APFETCH(A0, A1, 0)
  STAGE_DMA(0, lds0)
  __syncthreads();

  // ---- main loop: 4 chunks; DMA next chunk at chunk start; A prefetched 1 sub ahead ----
#pragma unroll
  for (int k = 0; k < 4; ++k) {
    char* rbuf = lds0 + (k & 1) * 24576;
    char* wbuf = lds0 + ((k & 1) ^ 1) * 24576;
    const int q0 = k * 3;

    // sub 0: prefetch A(q0+1) (older than DMAs), issue DMA for chunk k+1, compute
    APFETCH(N0, N1, q0 + 1)
    if (k < 3) STAGE_DMA(k + 1, wbuf)
    COMPUTE_SUB_DMA(0, rbuf, A0, A1)
#pragma unroll
    for (int dx = 0; dx < 3; ++dx) { A0[dx] = N0[dx]; A1[dx] = N1[dx]; }

    // sub 1
    APFETCH(N0, N1, q0 + 2)
    COMPUTE_SUB_DMA(1, rbuf, A0, A1)
#pragma unroll
    for (int dx = 0; dx < 3; ++dx) { A0[dx] = N0[dx]; A1[dx] = N1[dx]; }

    // sub 2
    if (k < 3) APFETCH(N0, N1, q0 + 3)
    COMPUTE_SUB_DMA(2, rbuf, A0, A1)
    if (k < 3) {
#pragma unroll
      for (int dx = 0; dx < 3; ++dx) { A0[dx] = N0[dx]; A1[dx] = N1[dx]; }
      __syncthreads();   // drains DMAs for chunk k+1 (compiler vmcnt at barrier)
    }
  }

  // ---- epilogue: C/D map col=lane&15, row=(lane>>4)*4+j ----
  const int obase = wv * 32 + lk4 * 4;
  float* outp = Out + (size_t)b * O_CH * PLANE + (size_t)y * HW;
#pragma unroll
  for (int mr = 0; mr < 2; ++mr) {
#pragma unroll
    for (int j = 0; j < 4; ++j) {
      const int o = obase + mr * 16 + j;
      float* po = outp + (size_t)o * PLANE;
#pragma unroll
      for (int nf = 0; nf < 7; ++nf) {
        po[nf * 16 + ln] = acc[mr][nf][j];
      }
    }
  }
#undef STAGE_DMA
#undef APFETCH
#undef COMPUTE_SUB_DMA
}

// ===================== fallback: R9 conv (verbatim) =====================
#define BUFB_F (3 * NCOL * 64)

__global__ __launch_bounds__(256, 3)
void conv_r9(const float* __restrict__ X,
             const unsigned short* __restrict__ Wb,
             float* __restrict__ Out) {
  __shared__ unsigned short Xs[2 * 3 * NCOL * 32];
  char* lds = (char*)Xs;

  const int bid = blockIdx.x;
  const int L = (bid & 7) * 448 + (bid >> 3);
  const int b = L / HW;
  const int y = L - b * HW;

  const int t   = threadIdx.x;
  const int wv  = t >> 6;
  const int l   = t & 63;
  const int ln  = l & 15;
  const int lk4 = l >> 4;

  const int c    = t & 127;
  const int chb  = (t >> 7) * 16;
  const int icol = c - 1;
  const bool cok = (c < NCOL);
  const int wxor = (c >> 1) & 3;

  f32x4 acc[2][7];
#pragma unroll
  for (int mr = 0; mr < 2; ++mr)
#pragma unroll
    for (int nf = 0; nf < 7; ++nf)
      acc[mr][nf] = (f32x4)0.0f;

  const unsigned short* wbase = Wb + (wv * 32 + ln) * I_CH + lk4 * 8;

#define LOAD16_F(V, KCH, SUB)                                                   \
  {                                                                             \
    const int row_ = y + (SUB)-1;                                               \
    const bool ok_ = (row_ >= 0) && (row_ < HW) && (icol >= 0) && (icol < HW);  \
    const float* sp_ = X + ((size_t)(b * I_CH + (KCH) + chb) * HW + row_) * HW  \
                       + icol;                                                  \
    _Pragma("unroll") for (int j = 0; j < 16; ++j) V[j] = 0.0f;                 \
    if (ok_) {                                                                  \
      _Pragma("unroll") for (int j = 0; j < 16; ++j) V[j] = sp_[j * PLANE];     \
    }                                                                           \
  }

#define WRITE16_F(V, SUB, WB)                                                   \
  if (cok) {                                                                    \
    const int base_ = ((SUB)*NCOL + c) * 64;                                    \
    _Pragma("unroll") for (int q = 0; q < 2; ++q) {                             \
      union { ushort8_t s; unsigned u[4]; } pk_;                                \
      pk_.u[0] = pktrunc(V[q * 8 + 0], V[q * 8 + 1]);                           \
      pk_.u[1] = pktrunc(V[q * 8 + 2], V[q * 8 + 3]);                           \
      pk_.u[2] = pktrunc(V[q * 8 + 4], V[q * 8 + 5]);                           \
      pk_.u[3] = pktrunc(V[q * 8 + 6], V[q * 8 + 7]);                           \
      const int slot_ = ((chb >> 3) + q) ^ wxor;                                \
      *reinterpret_cast<ushort8_t*>((WB) + base_ + slot_ * 16) = pk_.s;         \
    }                                                                           \
  }

#define APFETCH_F(D0, D1, Q)                                                    \
  _Pragma("unroll") for (int dx = 0; dx < 3; ++dx) {                            \
    const unsigned short* wp_ = wbase + (((Q) % 3) * 3 + dx) * (O_CH * I_CH)    \
                              + ((Q) / 3) * 32;                                 \
    D0[dx] = *reinterpret_cast<const short8*>(wp_);                             \
    D1[dx] = *reinterpret_cast<const short8*>(wp_ + 16 * I_CH);                 \
  }

#define COMPUTE_F(SUB, RB, S0, S1)                                              \
  _Pragma("unroll") for (int dx = 0; dx < 3; ++dx) {                            \
    const int q_ = dx + ln;                                                     \
    const int rslot_ = lk4 ^ ((q_ >> 1) & 3);                                   \
    const char* bp_ = (RB) + ((SUB)*NCOL + q_) * 64 + rslot_ * 16;              \
    _Pragma("unroll") for (int nf = 0; nf < 7; ++nf) {                          \
      short8 bb_ = *reinterpret_cast<const short8*>(bp_ + nf * 1024);           \
      acc[0][nf] = __builtin_amdgcn_mfma_f32_16x16x32_bf16(S0[dx], bb_, acc[0][nf], 0, 0, 0); \
      acc[1][nf] = __builtin_amdgcn_mfma_f32_16x16x32_bf16(S1[dx], bb_, acc[1][nf], 0, 0, 0); \
    }                                                                           \
  }

  short8 A0[3], A1[3], N0[3], N1[3];
  {
    float P0[16], P1[16], P2[16];
    LOAD16_F(P0, 0, 0)
    LOAD16_F(P1, 0, 1)
    LOAD16_F(P2, 0, 2)
    APFETCH_F(A0, A1, 0)
    WRITE16_F(P0, 0, lds)
    WRITE16_F(P1, 1, lds)
    WRITE16_F(P2, 2, lds)
  }
  __syncthreads();

#pragma unroll
  for (int k = 0; k < 4; ++k) {
    char* rbuf = lds + (k & 1) * BUFB_F;
    char* wbuf = lds + ((k & 1) ^ 1) * BUFB_F;
    float LA[16], LB[16];
    const int q0 = k * 3;

    if (k < 3) LOAD16_F(LA, (k + 1) * 32, 0)
    APFETCH_F(N0, N1, q0 + 1)
    COMPUTE_F(0, rbuf, A0, A1)
#pragma unroll
    for (int dx = 0; dx < 3; ++dx) { A0[dx] = N0[dx]; A1[dx] = N1[dx]; }

    if (k < 3) LOAD16_F(LB, (k + 1) * 32, 1)
    APFETCH_F(N0, N1, q0 + 2)
    COMPUTE_F(1, rbuf, A0, A1)
    if (k < 3) WRITE16_F(LA, 0, wbuf)
#pragma unroll
    for (int dx = 0; dx < 3; ++dx) { A0[dx] = N0[dx]; A1[dx] = N1[dx]; }

    if (k < 3) LOAD16_F(LA, (k + 1) * 32, 2)
    if (k < 3) APFETCH_F(N0, N1, q0 + 3)
    COMPUTE_F(2, rbuf, A0, A1)
    if (k < 3) {
      WRITE16_F(LB, 1, wbuf)
      WRITE16_F(LA, 2, wbuf)
#pragma unroll
      for (int dx = 0; dx < 3; ++dx) { A0[dx] = N0[dx]; A1[dx] = N1[dx]; }
      __syncthreads();
    }
  }

  const int obase = wv * 32 + lk4 * 4;
  float* outp = Out + (size_t)b * O_CH * PLANE + (size_t)y * HW;
#pragma unroll
  for (int mr = 0; mr < 2; ++mr) {
#pragma unroll
    for (int j = 0; j < 4; ++j) {
      const int o = obase + mr * 16 + j;
      float* po = outp + (size_t)o * PLANE;
#pragma unroll
      for (int nf = 0; nf < 7; ++nf) {
        po[nf * 16 + ln] = acc[mr][nf][j];
      }
    }
  }
}

extern "C" void kernel_launch(void* const* d_in, const int* in_sizes, int n_in,
                              void* d_out, int out_size, void* d_ws, size_t ws_size,
                              hipStream_t stream) {
  const float* x      = (const float*)d_in[0];
  const float* core   = (const float*)d_in[1];
  const float* periph = (const float*)d_in[2];
  const float* thr    = (const float*)d_in[3];
  const float* scale  = (const float*)d_in[4];

  if (ws_size >= WS_NEED) {
    unsigned short* Wb = (unsigned short*)((char*)d_ws + WB_OFF);
    unsigned short* Xp = (unsigned short*)((char*)d_ws + XP_OFF);
    wsynth_kernel<<<(O_CH * I_CH + 255) / 256, 256, 0, stream>>>(core, periph, thr, scale, Wb);
    zfill_kernel<<<1, 256, 0, stream>>>((float*)d_ws);
    xprep_kernel<<<32 * HW * 2, 256, 0, stream>>>(x, Xp);
    conv_dma<<<32 * HW, 256, 0, stream>>>(Xp, Wb, (const char*)d_ws, (float*)d_out);
  } else {
    unsigned short* Wb = (unsigned short*)d_ws;
    wsynth_kernel<<<(O_CH * I_CH + 255) / 256, 256, 0, stream>>>(core, periph, thr, scale, Wb);
    conv_r9<<<32 * HW, 256, 0, stream>>>(x, Wb, (float*)d_out);
  }
}